// Round 12
// baseline (794.648 us; speedup 1.0000x reference)
//
#include <hip/hip_runtime.h>
#include <hip/hip_fp16.h>

#define T_STEPS 336
#define NWG 32

typedef unsigned long long u64;

// Device-global scratch; sync state re-initialized every call (device globals
// survive across graph replays; stale tags would break the poll).
__device__ float g_h[337 * 512];      // h_1..h_336 (head reads t>=81)
__device__ float g_blw[256 * 512];    // sampled BayesianLinear weight
__device__ float g_blb[256];          // sampled BayesianLinear bias
__device__ u64   g_hh[2][512];        // parity buffers: (tag<<32)|h_bits

__device__ __forceinline__ float softplus_f(float x) {
  return (x > 20.f) ? x : log1pf(__expf(x));
}
__device__ __forceinline__ float sigmoid_f(float x) {
  return 1.f / (1.f + __expf(-x));
}
__device__ __forceinline__ float tanh_f(float x) {
  x = fminf(fmaxf(x, -15.f), 15.f);
  float e = __expf(-2.f * x);
  return (1.f - e) / (1.f + e);
}

// 3-deep pipelined poll, IC transport. ROUND-11 BUG FIXED: loads MUST carry
// sc1 (L1+L2 bypass -> served by the Infinity Cache, where agent-scope
// publishes land). Plain loads hit the polling XCD's own L2, which is never
// invalidated by a remote XCD's store -> infinite spin (the round-11 hang).
// Three loads stay in flight; checks run at vmcnt(2) -> detect granularity
// ~RTT/3. vmcnt drains oldest-first (m135), so the publisher's outstanding
// stores (older) only make the first wait slightly conservative. Tags
// strictly increase -> stale ring values can only mismatch. Exit drains
// vmcnt(0) so no in-flight load lands after the ring registers are reused.
// s22 iteration cap: degrade to wrong-answer instead of hang (never fires
// when transport is correct; 2^18 iters ~ 100 ms).
__device__ __forceinline__ unsigned poll_slot(const u64* slot, unsigned t) {
  unsigned lo;
  asm volatile(
    "s_mov_b32 s22, 0x40000\n\t"
    "global_load_dwordx2 v[60:61], %[p], off sc1\n\t"
    "global_load_dwordx2 v[62:63], %[p], off sc1\n\t"
    "global_load_dwordx2 v[64:65], %[p], off sc1\n\t"
    "POLL%=:\n\t"
    "s_sub_u32 s22, s22, 1\n\t"
    "s_cbranch_scc1 DA%=\n\t"          // cap exhausted -> bail with v60 (garbage beats hang)
    "s_waitcnt vmcnt(2)\n\t"
    "v_cmp_eq_u32 vcc, %[t], v61\n\t"
    "s_not_b64 s[20:21], vcc\n\t"
    "s_cbranch_scc0 DA%=\n\t"
    "global_load_dwordx2 v[60:61], %[p], off sc1\n\t"
    "s_waitcnt vmcnt(2)\n\t"
    "v_cmp_eq_u32 vcc, %[t], v63\n\t"
    "s_not_b64 s[20:21], vcc\n\t"
    "s_cbranch_scc0 DB%=\n\t"
    "global_load_dwordx2 v[62:63], %[p], off sc1\n\t"
    "s_waitcnt vmcnt(2)\n\t"
    "v_cmp_eq_u32 vcc, %[t], v65\n\t"
    "s_not_b64 s[20:21], vcc\n\t"
    "s_cbranch_scc0 DC%=\n\t"
    "global_load_dwordx2 v[64:65], %[p], off sc1\n\t"
    "s_branch POLL%=\n\t"
    "DA%=:\n\t"
    "v_mov_b32 %[lo], v60\n\t"
    "s_branch DONE%=\n\t"
    "DB%=:\n\t"
    "v_mov_b32 %[lo], v62\n\t"
    "s_branch DONE%=\n\t"
    "DC%=:\n\t"
    "v_mov_b32 %[lo], v64\n\t"
    "DONE%=:\n\t"
    "s_waitcnt vmcnt(0)"
    : [lo] "=v"(lo)
    : [p] "v"(slot), [t] "s"(t)
    : "v60","v61","v62","v63","v64","v65","vcc","s20","s21","s22","memory");
  return lo;
}

// ---------------- init: BLb sampling + g_hh tag init (1 block) ----------------
__global__ __launch_bounds__(256) void init_kernel(
    const float* __restrict__ blb_mu, const float* __restrict__ blb_rho,
    const float* __restrict__ eps_blb)
{
  const int tid = threadIdx.x;
  g_blb[tid] = blb_mu[tid] + softplus_f(blb_rho[tid]) * eps_blb[tid];
  u64* p = &g_hh[0][0];
  #pragma unroll
  for (int q = 0; q < 4; ++q)
    __hip_atomic_store(p + q * 256 + tid, 0ULL, __ATOMIC_RELAXED,
                       __HIP_MEMORY_SCOPE_AGENT);
}

// ---------------- persistent LSTM recurrence ----------------
// 32 WGs x 512 threads (proven IC transport). WG r owns h-indices [16r,16r+16).
// Thread (seg=tid>>6, cl=tid&63): col=(cl>>4)*512+16r+(cl&15),
// rows [64seg,64seg+64), 64 Whh weights in regs. Wave seg polls exactly the
// 64 slots its dot consumes (no poll->dot barrier); part[] parity-buffered ->
// single __syncthreads per step. Startup also samples BLW (head input).
__global__ __launch_bounds__(512) void lstm_kernel(
    const float* __restrict__ x, const float* __restrict__ drop_x,
    const float* __restrict__ wih_mu, const float* __restrict__ wih_rho, const float* __restrict__ eps_wih,
    const float* __restrict__ b_mu, const float* __restrict__ b_rho, const float* __restrict__ eps_b,
    const float* __restrict__ whh_mu, const float* __restrict__ whh_rho, const float* __restrict__ eps_whh,
    const float* __restrict__ blw_mu, const float* __restrict__ blw_rho, const float* __restrict__ eps_blw)
{
  const int r = blockIdx.x;         // 0..31
  const int tid = threadIdx.x;      // 0..511
  const int cl = tid & 63;
  const int seg = tid >> 6;         // 0..7
  const int gate = cl >> 4, kl = cl & 15;
  const int col = gate * 512 + r * 16 + kl;
  const int row0 = seg * 64;

  __shared__ float  xd[336 * 16];   // x*drop_x for batch 255
  __shared__ __half hs16[512];      // fp16 h copy (matvec input only)
  __shared__ float  part[2][8][64]; // parity-double-buffered partials

  // One-time: sample BLW (consumed by head after this kernel completes).
  {
    const int e0 = (r * 512 + tid) * 8;
    #pragma unroll
    for (int q = 0; q < 8; ++q) {
      const int e = e0 + q;
      g_blw[e] = blw_mu[e] + softplus_f(blw_rho[e]) * eps_blw[e];
    }
  }

  for (int e = tid; e < 5376; e += 512) {
    const int src = 255 * 5376 + e;   // batch-255 slice is contiguous
    xd[e] = x[src] * drop_x[src];
  }

  // 64 sampled Whh weights in registers (FULL unroll or w[] demotes to scratch).
  float w[64];
  #pragma unroll
  for (int j = 0; j < 64; ++j) {
    const int idx = (row0 + j) * 2048 + col;
    w[j] = whh_mu[idx] + softplus_f(whh_rho[idx]) * eps_whh[idx];
  }

  // Wave 0: Wih column + bias for on-the-fly xg.
  float wih[16];
  float bias = 0.f;
  if (tid < 64) {
    bias = b_mu[col] + softplus_f(b_rho[col]) * eps_b[col];
    #pragma unroll
    for (int i = 0; i < 16; ++i) {
      const int idx = i * 2048 + col;
      wih[i] = wih_mu[idx] + softplus_f(wih_rho[idx]) * eps_wih[idx];
    }
  }
  __syncthreads();                  // xd staged

  auto xg_at = [&](int t) -> float {
    const float4* xr = (const float4*)(xd + t * 16);
    float4 x0 = xr[0], x1 = xr[1], x2 = xr[2], x3 = xr[3];
    float s0 = fmaf(x0.x, wih[0], bias);
    s0 = fmaf(x0.y, wih[1], s0); s0 = fmaf(x0.z, wih[2], s0); s0 = fmaf(x0.w, wih[3], s0);
    float s1 = x1.x * wih[4];
    s1 = fmaf(x1.y, wih[5], s1); s1 = fmaf(x1.z, wih[6], s1); s1 = fmaf(x1.w, wih[7], s1);
    float s2 = x2.x * wih[8];
    s2 = fmaf(x2.y, wih[9], s2); s2 = fmaf(x2.z, wih[10], s2); s2 = fmaf(x2.w, wih[11], s2);
    float s3 = x3.x * wih[12];
    s3 = fmaf(x3.y, wih[13], s3); s3 = fmaf(x3.z, wih[14], s3); s3 = fmaf(x3.w, wih[15], s3);
    return (s0 + s1) + (s2 + s3);
  };

  float c = 0.f;                    // cell state (wave-0 lanes 0..15)
  float xgv = (tid < 64) ? xg_at(0) : 0.f;

  for (int t = 0; t < T_STEPS; ++t) {
    const int p = t & 1;

    // Pipelined IC poll of my slot (tag t carries the h value).
    {
      unsigned bits = poll_slot(&g_hh[p][tid], (unsigned)t);
      hs16[tid] = __float2half(__uint_as_float(bits));
    }
    // No barrier: wave seg's dot reads hs16[row0..row0+64) = its own lanes' data.

    float a0 = 0.f, a1 = 0.f, a2 = 0.f, a3 = 0.f;
    const float4* hv = (const float4*)(hs16 + row0);   // 8 halves per float4
    #pragma unroll
    for (int jj = 0; jj < 8; ++jj) {
      float4 q = hv[jj];
      const __half2* hp = (const __half2*)&q;
      float2 f0 = __half22float2(hp[0]);
      float2 f1 = __half22float2(hp[1]);
      float2 f2 = __half22float2(hp[2]);
      float2 f3 = __half22float2(hp[3]);
      a0 = fmaf(f0.x, w[8 * jj],     a0);
      a1 = fmaf(f0.y, w[8 * jj + 1], a1);
      a2 = fmaf(f1.x, w[8 * jj + 2], a2);
      a3 = fmaf(f1.y, w[8 * jj + 3], a3);
      a0 = fmaf(f2.x, w[8 * jj + 4], a0);
      a1 = fmaf(f2.y, w[8 * jj + 5], a1);
      a2 = fmaf(f3.x, w[8 * jj + 6], a2);
      a3 = fmaf(f3.y, w[8 * jj + 7], a3);
    }
    part[p][seg][cl] = (a0 + a1) + (a2 + a3);
    __syncthreads();   // single rendezvous per step (skew-safe via parity bufs)

    if (tid < 64) {
      float g = xgv
              + ((part[p][0][tid] + part[p][1][tid]) + (part[p][2][tid] + part[p][3][tid]))
              + ((part[p][4][tid] + part[p][5][tid]) + (part[p][6][tid] + part[p][7][tid]));
      // Parallel activation on all 64 lanes (one exp chain each).
      const bool is_g = (gate == 2);
      float xin = is_g ? 2.f * fminf(fmaxf(g, -15.f), 15.f) : g;
      float s = sigmoid_f(xin);
      float act = is_g ? 2.f * s - 1.f : s;
      float vi = __shfl(act, kl);
      float vf = __shfl(act, kl + 16);
      float vg = __shfl(act, kl + 32);
      float vo = __shfl(act, kl + 48);
      if (tid < 16) {
        c = vf * c + vi * vg;
        float h = vo * tanh_f(c);
        const int idx = r * 16 + tid;
        u64 pv = (((u64)(unsigned)(t + 1)) << 32) | (u64)__float_as_uint(h);
        __hip_atomic_store(&g_hh[(t + 1) & 1][idx], pv,
                           __ATOMIC_RELAXED, __HIP_MEMORY_SCOPE_AGENT);
        g_h[(t + 1) * 512 + idx] = h;                  // for head (after publish)
      }
      if (t + 1 < T_STEPS) xgv = xg_at(t + 1);         // off critical path
    }
  }
}

// ---------------- head ----------------
// block j: last[j] = g_h[81+j]  (reshape(T,B,H)[-1] => h_{t=80+j} of batch 255)
// y[l] = relu(last*drop_h[j] . BLW[l] + BLb[l]) * drop_l[j,l]
// out[j,o] = sum_l y[l]*lin_w[o,l]
__global__ __launch_bounds__(256) void head_kernel(
    const float* __restrict__ drop_h, const float* __restrict__ drop_l,
    const float* __restrict__ lin_w, float* __restrict__ out)
{
  const int j = blockIdx.x, tid = threadIdx.x;
  __shared__ float hd[512];
  __shared__ float y[256];

  for (int k = tid; k < 512; k += 256)
    hd[k] = g_h[(81 + j) * 512 + k] * drop_h[j * 512 + k];
  __syncthreads();

  {
    const int l = tid;
    float acc = g_blb[l];
    const float* wrow = g_blw + l * 512;
    #pragma unroll 8
    for (int k = 0; k < 512; ++k) acc = fmaf(hd[k], wrow[k], acc);
    acc = fmaxf(acc, 0.f);
    y[l] = acc * drop_l[j * 256 + l];
  }
  __syncthreads();

  if (tid < 10) {
    float acc = 0.f;
    const float* lrow = lin_w + tid * 256;
    #pragma unroll 8
    for (int l = 0; l < 256; ++l) acc = fmaf(y[l], lrow[l], acc);
    out[j * 10 + tid] = acc;
  }
}

// ---------------- launch ----------------
extern "C" void kernel_launch(void* const* d_in, const int* in_sizes, int n_in,
                              void* d_out, int out_size, void* d_ws, size_t ws_size,
                              hipStream_t stream) {
  const float* x        = (const float*)d_in[0];
  const float* drop_x   = (const float*)d_in[1];
  const float* drop_h   = (const float*)d_in[2];
  const float* drop_l   = (const float*)d_in[3];
  const float* wih_mu   = (const float*)d_in[4];
  const float* wih_rho  = (const float*)d_in[5];
  const float* eps_wih  = (const float*)d_in[6];
  const float* whh_mu   = (const float*)d_in[7];
  const float* whh_rho  = (const float*)d_in[8];
  const float* eps_whh  = (const float*)d_in[9];
  const float* b_mu     = (const float*)d_in[10];
  const float* b_rho    = (const float*)d_in[11];
  const float* eps_b    = (const float*)d_in[12];
  const float* blw_mu   = (const float*)d_in[13];
  const float* blw_rho  = (const float*)d_in[14];
  const float* eps_blw  = (const float*)d_in[15];
  const float* blb_mu   = (const float*)d_in[16];
  const float* blb_rho  = (const float*)d_in[17];
  const float* eps_blb  = (const float*)d_in[18];
  const float* lin_w    = (const float*)d_in[19];

  init_kernel<<<1, 256, 0, stream>>>(blb_mu, blb_rho, eps_blb);

  lstm_kernel<<<NWG, 512, 0, stream>>>(x, drop_x,
                                       wih_mu, wih_rho, eps_wih,
                                       b_mu, b_rho, eps_b,
                                       whh_mu, whh_rho, eps_whh,
                                       blw_mu, blw_rho, eps_blw);

  head_kernel<<<256, 256, 0, stream>>>(drop_h, drop_l, lin_w, (float*)d_out);
}

// Round 13
// 722.805 us; speedup vs baseline: 1.0994x; 1.0994x over previous
//
#include <hip/hip_runtime.h>

#define T_STEPS 336
#define NWG 32

typedef unsigned long long u64;

// Device-global scratch. g_hh slot tags are re-initialized by their OWNING WG
// at lstm startup each call (first call: .bss zeros = tag0|h0=0, exactly the
// valid t=0 state; later calls: stale tags 336/335 never match targets 0/1).
__device__ float g_h[337 * 512];      // h_1..h_336 (head reads t>=81)
__device__ float g_blw[256 * 512];    // sampled BayesianLinear weight
__device__ u64   g_hh[2][512];        // parity buffers: (tag<<32)|h_bits

__device__ __forceinline__ float softplus_f(float x) {
  return (x > 20.f) ? x : log1pf(__expf(x));
}
__device__ __forceinline__ float sigmoid_f(float x) {
  return 1.f / (1.f + __expf(-x));
}
__device__ __forceinline__ float tanh_f(float x) {
  x = fminf(fmaxf(x, -15.f), 15.f);
  float e = __expf(-2.f * x);
  return (1.f - e) / (1.f + e);
}

// ---------------- persistent LSTM recurrence ----------------
// 32 WGs x 512 threads; proven IC transport (relaxed agent atomics; the only
// config with zero outliers across rounds 6/7/9/10). WG r owns h-indices
// [16r,16r+16). Thread (seg=tid>>6, cl=tid&63): col=(cl>>4)*512+16r+(cl&15),
// rows [64seg,64seg+64), 64 sampled Whh weights in registers (FULL unroll or
// w[] demotes to scratch -- round-5 lesson). Wave seg polls exactly the 64
// h-slots its dot consumes -> no poll->dot barrier; part[] parity-double-
// buffered -> single __syncthreads per step. Per-step cost is pinned by the
// IC store->remote-load wall latency (~1.85us); compute hides under it, which
// is why fp16 dots / pipelined polls / finer quanta all failed to move it.
__global__ __launch_bounds__(512) void lstm_kernel(
    const float* __restrict__ x, const float* __restrict__ drop_x,
    const float* __restrict__ wih_mu, const float* __restrict__ wih_rho, const float* __restrict__ eps_wih,
    const float* __restrict__ b_mu, const float* __restrict__ b_rho, const float* __restrict__ eps_b,
    const float* __restrict__ whh_mu, const float* __restrict__ whh_rho, const float* __restrict__ eps_whh,
    const float* __restrict__ blw_mu, const float* __restrict__ blw_rho, const float* __restrict__ eps_blw)
{
  const int r = blockIdx.x;         // 0..31
  const int tid = threadIdx.x;      // 0..511
  const int cl = tid & 63;
  const int seg = tid >> 6;         // 0..7
  const int gate = cl >> 4, kl = cl & 15;
  const int col = gate * 512 + r * 16 + kl;
  const int row0 = seg * 64;

  // FIRST: re-tag my own 16 slots for t=0 (both parities). Owners-only ->
  // no cross-WG write races; consumers' t=0 polls wait for these stores.
  if (tid < 16) {
    const int idx = r * 16 + tid;
    __hip_atomic_store(&g_hh[0][idx], 0ULL, __ATOMIC_RELAXED, __HIP_MEMORY_SCOPE_AGENT);
    __hip_atomic_store(&g_hh[1][idx], 0ULL, __ATOMIC_RELAXED, __HIP_MEMORY_SCOPE_AGENT);
  }

  __shared__ float xd[336 * 16];    // x*drop_x for batch 255
  __shared__ float hs[512];         // fp32 h copy (wave-local segments)
  __shared__ float part[2][8][64];  // parity-double-buffered partials

  // One-time: sample BLW (consumed by head after this kernel completes).
  {
    const int e0 = (r * 512 + tid) * 8;
    #pragma unroll
    for (int q = 0; q < 8; ++q) {
      const int e = e0 + q;
      g_blw[e] = blw_mu[e] + softplus_f(blw_rho[e]) * eps_blw[e];
    }
  }

  for (int e = tid; e < 5376; e += 512) {
    const int src = 255 * 5376 + e;   // batch-255 slice is contiguous
    xd[e] = x[src] * drop_x[src];
  }

  // 64 sampled Whh weights into registers.
  float w[64];
  #pragma unroll
  for (int j = 0; j < 64; ++j) {
    const int idx = (row0 + j) * 2048 + col;
    w[j] = whh_mu[idx] + softplus_f(whh_rho[idx]) * eps_whh[idx];
  }

  // Wave 0: Wih column + bias for on-the-fly xg.
  float wih[16];
  float bias = 0.f;
  if (tid < 64) {
    bias = b_mu[col] + softplus_f(b_rho[col]) * eps_b[col];
    #pragma unroll
    for (int i = 0; i < 16; ++i) {
      const int idx = i * 2048 + col;
      wih[i] = wih_mu[idx] + softplus_f(wih_rho[idx]) * eps_wih[idx];
    }
  }
  __syncthreads();                  // xd staged

  auto xg_at = [&](int t) -> float {
    const float4* xr = (const float4*)(xd + t * 16);
    float4 x0 = xr[0], x1 = xr[1], x2 = xr[2], x3 = xr[3];
    float s0 = fmaf(x0.x, wih[0], bias);
    s0 = fmaf(x0.y, wih[1], s0); s0 = fmaf(x0.z, wih[2], s0); s0 = fmaf(x0.w, wih[3], s0);
    float s1 = x1.x * wih[4];
    s1 = fmaf(x1.y, wih[5], s1); s1 = fmaf(x1.z, wih[6], s1); s1 = fmaf(x1.w, wih[7], s1);
    float s2 = x2.x * wih[8];
    s2 = fmaf(x2.y, wih[9], s2); s2 = fmaf(x2.z, wih[10], s2); s2 = fmaf(x2.w, wih[11], s2);
    float s3 = x3.x * wih[12];
    s3 = fmaf(x3.y, wih[13], s3); s3 = fmaf(x3.z, wih[14], s3); s3 = fmaf(x3.w, wih[15], s3);
    return (s0 + s1) + (s2 + s3);
  };

  float c = 0.f;                    // cell state (wave-0 lanes 0..15)
  float xgv = (tid < 64) ? xg_at(0) : 0.f;

  for (int t = 0; t < T_STEPS; ++t) {
    const int p = t & 1;

    // Poll my slot at IC (proven transport); tag t carries the h value.
    {
      const u64* slot = &g_hh[p][tid];
      u64 v;
      int it = 0;
      for (;;) {
        v = __hip_atomic_load(slot, __ATOMIC_RELAXED, __HIP_MEMORY_SCOPE_AGENT);
        if ((unsigned)(v >> 32) == (unsigned)t) break;
        if (++it > (1 << 22)) break;   // anti-hang insurance (never fires in practice)
      }
      hs[tid] = __uint_as_float((unsigned)v);
    }
    // No barrier: wave seg's dot reads hs[row0..row0+64) = its own lanes' data.

    float a0 = 0.f, a1 = 0.f, a2 = 0.f, a3 = 0.f;
    const float4* hv = (const float4*)(hs + row0);
    #pragma unroll
    for (int jj = 0; jj < 16; ++jj) {
      float4 h4 = hv[jj];
      a0 = fmaf(h4.x, w[4 * jj],     a0);
      a1 = fmaf(h4.y, w[4 * jj + 1], a1);
      a2 = fmaf(h4.z, w[4 * jj + 2], a2);
      a3 = fmaf(h4.w, w[4 * jj + 3], a3);
    }
    part[p][seg][cl] = (a0 + a1) + (a2 + a3);
    __syncthreads();   // single rendezvous per step (skew-safe via parity bufs)

    if (tid < 64) {
      float g = xgv
              + ((part[p][0][tid] + part[p][1][tid]) + (part[p][2][tid] + part[p][3][tid]))
              + ((part[p][4][tid] + part[p][5][tid]) + (part[p][6][tid] + part[p][7][tid]));
      // Parallel activation on all 64 lanes (one exp chain each):
      // gates i,f,o -> sigmoid; gate g -> tanh = 2*sigmoid(2x)-1 (clamped).
      const bool is_g = (gate == 2);
      float xin = is_g ? 2.f * fminf(fmaxf(g, -15.f), 15.f) : g;
      float s = sigmoid_f(xin);
      float act = is_g ? 2.f * s - 1.f : s;
      float vi = __shfl(act, kl);
      float vf = __shfl(act, kl + 16);
      float vg = __shfl(act, kl + 32);
      float vo = __shfl(act, kl + 48);
      if (tid < 16) {
        c = vf * c + vi * vg;
        float h = vo * tanh_f(c);
        const int idx = r * 16 + tid;
        u64 pv = (((u64)(unsigned)(t + 1)) << 32) | (u64)__float_as_uint(h);
        __hip_atomic_store(&g_hh[(t + 1) & 1][idx], pv,
                           __ATOMIC_RELAXED, __HIP_MEMORY_SCOPE_AGENT);   // publish first
        g_h[(t + 1) * 512 + idx] = h;                  // for head (kernel-end flush)
      }
      if (t + 1 < T_STEPS) xgv = xg_at(t + 1);         // off critical path
    }
  }
}

// ---------------- head ----------------
// block j: last[j] = g_h[81+j]  (reshape(T,B,H)[-1] => h_{t=80+j} of batch 255)
// y[l] = relu(last*drop_h[j] . BLW[l] + BLb[l]) * drop_l[j,l]; out = y @ lin_w^T.
// BLb sampled inline per block (256 redundant softplus -- free).
__global__ __launch_bounds__(256) void head_kernel(
    const float* __restrict__ drop_h, const float* __restrict__ drop_l,
    const float* __restrict__ blb_mu, const float* __restrict__ blb_rho,
    const float* __restrict__ eps_blb,
    const float* __restrict__ lin_w, float* __restrict__ out)
{
  const int j = blockIdx.x, tid = threadIdx.x;
  __shared__ float hd[512];
  __shared__ float y[256];

  for (int k = tid; k < 512; k += 256)
    hd[k] = g_h[(81 + j) * 512 + k] * drop_h[j * 512 + k];
  __syncthreads();

  {
    const int l = tid;
    float acc = blb_mu[l] + softplus_f(blb_rho[l]) * eps_blb[l];
    const float* wrow = g_blw + l * 512;
    #pragma unroll 8
    for (int k = 0; k < 512; ++k) acc = fmaf(hd[k], wrow[k], acc);
    acc = fmaxf(acc, 0.f);
    y[l] = acc * drop_l[j * 256 + l];
  }
  __syncthreads();

  if (tid < 10) {
    float acc = 0.f;
    const float* lrow = lin_w + tid * 256;
    #pragma unroll 8
    for (int l = 0; l < 256; ++l) acc = fmaf(y[l], lrow[l], acc);
    out[j * 10 + tid] = acc;
  }
}

// ---------------- launch (2 dispatches) ----------------
extern "C" void kernel_launch(void* const* d_in, const int* in_sizes, int n_in,
                              void* d_out, int out_size, void* d_ws, size_t ws_size,
                              hipStream_t stream) {
  const float* x        = (const float*)d_in[0];
  const float* drop_x   = (const float*)d_in[1];
  const float* drop_h   = (const float*)d_in[2];
  const float* drop_l   = (const float*)d_in[3];
  const float* wih_mu   = (const float*)d_in[4];
  const float* wih_rho  = (const float*)d_in[5];
  const float* eps_wih  = (const float*)d_in[6];
  const float* whh_mu   = (const float*)d_in[7];
  const float* whh_rho  = (const float*)d_in[8];
  const float* eps_whh  = (const float*)d_in[9];
  const float* b_mu     = (const float*)d_in[10];
  const float* b_rho    = (const float*)d_in[11];
  const float* eps_b    = (const float*)d_in[12];
  const float* blw_mu   = (const float*)d_in[13];
  const float* blw_rho  = (const float*)d_in[14];
  const float* eps_blw  = (const float*)d_in[15];
  const float* blb_mu   = (const float*)d_in[16];
  const float* blb_rho  = (const float*)d_in[17];
  const float* eps_blb  = (const float*)d_in[18];
  const float* lin_w    = (const float*)d_in[19];

  lstm_kernel<<<NWG, 512, 0, stream>>>(x, drop_x,
                                       wih_mu, wih_rho, eps_wih,
                                       b_mu, b_rho, eps_b,
                                       whh_mu, whh_rho, eps_whh,
                                       blw_mu, blw_rho, eps_blw);

  head_kernel<<<256, 256, 0, stream>>>(drop_h, drop_l,
                                       blb_mu, blb_rho, eps_blb,
                                       lin_w, (float*)d_out);
}